// Round 17
// baseline (126.571 us; speedup 1.0000x reference)
//
#include <hip/hip_runtime.h>
#include <hip/hip_bf16.h>

#define Bsz 4
#define Ssz 2048
#define Esz 1024
#define Hsz 16
#define DHsz 64

// KV tile (64 keys, fp16): K 8KB | VT 8KB | padflag(f32) 256B
#define TILE_B 16640
#define NKT    (Ssz / 64)                    // 32 tiles max (~17 used)
#define WT_OFF   34078720                    // 256 W tiles x 8KB = 2MB
#define X_OFF    36175872                    // X tile images: 1024 x 16KB = 16MB
#define NKEPT_OFF 52953088                   // 4 ints

typedef _Float16 f16x8 __attribute__((ext_vector_type(8)));
typedef float    f32x4  __attribute__((ext_vector_type(4)));
typedef float    f32x16 __attribute__((ext_vector_type(16)));
typedef unsigned int u32;
typedef u32 u32x2 __attribute__((ext_vector_type(2)));
typedef u32 u32x4 __attribute__((ext_vector_type(4)));

static __device__ __forceinline__ f32x16 mfma32(f16x8 a, f16x8 b, f32x16 c) {
    return __builtin_amdgcn_mfma_f32_32x32x16_f16(a, b, c, 0, 0, 0);
}
static __device__ __forceinline__ f32x4 mfma16h(f16x8 a, f16x8 b, f32x4 c) {
    return __builtin_amdgcn_mfma_f32_16x16x32_f16(a, b, c, 0, 0, 0);
}

// Explicit drain before barrier (rule #18): replay-safe dbuf.
static __device__ __forceinline__ void drain_barrier() {
    asm volatile("s_waitcnt vmcnt(0) lgkmcnt(0)" ::: "memory");
    __builtin_amdgcn_sched_barrier(0);
    __syncthreads();
}

// 64x64 fp16 tile in 256B rows (2 keys/row, 16 slots of 16B); conflict-free
// (SQ_LDS_BANK_CONFLICT == 0 measured, rounds 8-16).
static __device__ __forceinline__ char* kvslot(char* base, int r2, int p, int j) {
    int s = ((((j & 4) << 1) | (p << 2) | (j & 3)) ^ (r2 & 15));
    return base + r2 * 256 + (s << 4);
}
static __device__ __forceinline__ const char* kvslotc(const char* base, int r2, int p, int j) {
    int s = ((((j & 4) << 1) | (p << 2) | (j & 3)) ^ (r2 & 15));
    return base + r2 * 256 + (s << 4);
}

// 128B-row swizzle (out_gemm 16x16 fragments: 2-way = free).
static __device__ __forceinline__ char* swz(char* base, int row, int colByte) {
    return base + row * 128 + (colByte ^ ((row & 7) << 4));
}

typedef const unsigned int __attribute__((address_space(1))) as1_u32;
typedef unsigned int __attribute__((address_space(3))) as3_u32;
static __device__ __forceinline__ void gl_lds16(const void* g, void* l) {
    __builtin_amdgcn_global_load_lds((as1_u32*)g, (as3_u32*)l, 16, 0, 0);
}
static __device__ __forceinline__ void gl_lds4(const void* g, void* l) {
    __builtin_amdgcn_global_load_lds((as1_u32*)g, (as3_u32*)l, 4, 0, 0);
}

static __device__ __forceinline__ float fexp2(float x) {
#if __has_builtin(__builtin_amdgcn_exp2f)
    return __builtin_amdgcn_exp2f(x);
#else
    return __expf(x * 0.6931471805599453f);
#endif
}
static __device__ __forceinline__ float frcp(float x) {
#if __has_builtin(__builtin_amdgcn_rcpf)
    return __builtin_amdgcn_rcpf(x);
#else
    return __fdividef(1.0f, x);
#endif
}

// ---------- prepass (single launch): z<4 -> KV gather (inline mask scan);
//                                     z==4 -> W fp32->fp16 tile images ----------
__global__ __launch_bounds__(256) void prep_all(
    const float* __restrict__ K, const float* __restrict__ V,
    const int* __restrict__ mask, const float* __restrict__ scale_p,
    const float* __restrict__ W,
    char* __restrict__ KVt, char* __restrict__ Wt, int* __restrict__ nkept)
{
    const int tid = threadIdx.x;

    if (blockIdx.z == Bsz) {   // ---- W conversion slice (256 of 512 blocks)
        const int w = blockIdx.y * 32 + blockIdx.x;
        if (w >= 256) return;
        const int kt = w & 15, nt = w >> 4;
        char* tile = Wt + (size_t)(nt * 16 + kt) * 8192;
        const int n = tid >> 2, seg = tid & 3;
        const float* wp = W + (size_t)(nt * 64 + n) * Esz + kt * 64 + seg * 16;
        f16x8 t[2];
#pragma unroll
        for (int hf = 0; hf < 2; ++hf) {
            f32x4 a = *(const f32x4*)(wp + hf * 8);
            f32x4 c = *(const f32x4*)(wp + hf * 8 + 4);
#pragma unroll
            for (int i = 0; i < 8; ++i) t[hf][i] = (_Float16)((i < 4) ? a[i] : c[i - 4]);
        }
        const int x = (n & 7) << 4;
        *(f16x8*)(tile + n * 128 + ((seg * 32) ^ x))      = t[0];
        *(f16x8*)(tile + n * 128 + ((seg * 32 + 16) ^ x)) = t[1];
        return;
    }

    // ---- KV slice: inline per-block compaction scan (wave 0), then gather
    const int kt = blockIdx.x, h = blockIdx.y, b = blockIdx.z;
    __shared__ int kidx_s[Ssz];
    __shared__ int nk_s;

    if (tid < 64) {
        int mreg[32];
#pragma unroll
        for (int c = 0; c < 32; ++c)
            mreg[c] = mask[(size_t)b * Ssz + c * 64 + tid];
        int base = 0;
#pragma unroll
        for (int c = 0; c < 32; ++c) {
            const bool keep = (mreg[c] == 0);
            const unsigned long long bal = __ballot(keep);
            const int pos = base + (int)__popcll(bal & ((1ull << tid) - 1ull));
            if (keep) kidx_s[pos] = c * 64 + tid;
            base += (int)__popcll(bal);
        }
        if (tid == 0) {
            nk_s = base;
            if (kt == 0 && h == 0) nkept[b] = base;
        }
    }
    __syncthreads();
    const int nk = nk_s;
    if (kt >= ((nk + 63) >> 6)) return;

    char* tile = KVt + (size_t)((b * Hsz + h) * NKT + kt) * TILE_B;
    const float k1l2 = scale_p[0] * 0.25f * 1.4426950408889634f;  // folded QK scale

    {   // K: thread -> compact key i, d-chunks 2seg, 2seg+1
        const int i = tid >> 2, seg = tid & 3;
        const int jj = kt * 64 + i;
        f16x8 t[2] = {{0,0,0,0,0,0,0,0},{0,0,0,0,0,0,0,0}};
        if (jj < nk) {
            const int src = kidx_s[jj];
            const float* kp = K + ((size_t)b * Ssz + src) * Esz + h * DHsz + seg * 16;
#pragma unroll
            for (int hf = 0; hf < 2; ++hf) {
                f32x4 a = *(const f32x4*)(kp + hf * 8);
                f32x4 c = *(const f32x4*)(kp + hf * 8 + 4);
#pragma unroll
                for (int q = 0; q < 8; ++q)
                    t[hf][q] = (_Float16)(((q < 4) ? a[q] : c[q - 4]) * k1l2);
            }
        }
#pragma unroll
        for (int hf = 0; hf < 2; ++hf)
            *(f16x8*)kvslot(tile, i >> 1, i & 1, seg * 2 + hf) = t[hf];
    }
    {   // V^T: thread -> dh row d, compact key chunks 2ks, 2ks+1
        const int d = tid & 63, ks = tid >> 6;
        f16x8 t[2] = {{0,0,0,0,0,0,0,0},{0,0,0,0,0,0,0,0}};
#pragma unroll
        for (int j = 0; j < 16; ++j) {
            const int jj = kt * 64 + ks * 16 + j;
            if (jj < nk) {
                const int src = kidx_s[jj];
                t[j >> 3][j & 7] = (_Float16)V[((size_t)b * Ssz + src) * Esz + h * DHsz + d];
            }
        }
#pragma unroll
        for (int hf = 0; hf < 2; ++hf)
            *(f16x8*)kvslot(tile + 8192, d >> 1, d & 1, ks * 2 + hf) = t[hf];
    }
    if (tid < 64)
        *(float*)(tile + 16384 + tid * 4) = (kt * 64 + tid < nk) ? 0.0f : -100000.0f;
}

// ---------- fused attention: 256 q/block (8 waves) — frozen best geometry ----------
static __device__ __forceinline__ void stage(char* buf, const char* tile, int wid, int lane) {
#pragma unroll
    for (int i = 0; i < 2; ++i) {
        const int c = wid * 2 + i;
        gl_lds16(tile + c * 1024 + lane * 16, buf + c * 1024);
    }
    if (wid == 0)
        gl_lds4(tile + 16384 + lane * 4, buf + 16384);
}

__global__ __launch_bounds__(512, 4) void attn_kernel(
    const char* __restrict__ KVt, const float* __restrict__ Q,
    const int* __restrict__ nkept, const float* __restrict__ logC_p,
    char* __restrict__ Ximg)
{
    __shared__ __align__(16) char kvb[2][TILE_B];

    const int tid = threadIdx.x;
    const int l   = tid & 63;
    const int wid = tid >> 6;        // 8 waves, each owns 32 queries
    const int q32 = l & 31;
    const int hi  = l >> 5;

    // XCD-chunked swizzle: 8 q-blocks of one (b,h) -> same XCD
    const int orig = blockIdx.x;
    const int work = (orig & 7) * 64 + (orig >> 3);
    const int bh = work >> 3, qt = work & 7;
    const int b = bh >> 4, h = bh & 15;

    const float LOG2E = 1.4426950408889634f;
    const float C     = __expf(logC_p[0]);
    const float negl2 = -2.0f * C * LOG2E;        // p = 2^(negl2/(z+1) + padlog)
    const int   nkt   = (nkept[b] + 63) >> 6;     // dynamic tile count (~17)

    const char* tiles = KVt + (size_t)bh * NKT * TILE_B;

    // Q fragments: qf[ch][j] = Q[qt*256+wid*32+q32][ch*16 + hi*8 + j]
    f16x8 qf[4];
    {
        const float* qp = Q + ((size_t)b * Ssz + qt * 256 + wid * 32 + q32) * Esz + h * DHsz + hi * 8;
#pragma unroll
        for (int ch = 0; ch < 4; ++ch) {
            f32x4 v0 = *(const f32x4*)(qp + ch * 16);
            f32x4 v1 = *(const f32x4*)(qp + ch * 16 + 4);
#pragma unroll
            for (int i = 0; i < 8; ++i)
                qf[ch][i] = (_Float16)((i < 4) ? v0[i] : v1[i - 4]);
        }
    }

    const f16x8 ones = {(_Float16)1.f, (_Float16)1.f, (_Float16)1.f, (_Float16)1.f,
                        (_Float16)1.f, (_Float16)1.f, (_Float16)1.f, (_Float16)1.f};

    f32x16 oaccT[2], dacc;
#pragma unroll
    for (int t = 0; t < 2; ++t)
#pragma unroll
        for (int r = 0; r < 16; ++r) oaccT[t][r] = 0.0f;
#pragma unroll
    for (int r = 0; r < 16; ++r) dacc[r] = 0.0f;

    stage(kvb[0], tiles, wid, l);
    int cur = 0;
    for (int kt = 0; kt < nkt; ++kt) {
        drain_barrier();                       // buf[cur] fully staged for ALL waves
        if (kt < nkt - 1)
            stage(kvb[cur ^ 1], tiles + (size_t)(kt + 1) * TILE_B, wid, l);

        char* kb  = kvb[cur];
        char* vtb = kb + 8192;
        const char* mkb = kb + 16384;

#pragma unroll
        for (int ktile = 0; ktile < 2; ++ktile) {
            // ---- QK^T (swapped, K pre-scaled): D[key][query]
            f32x16 sacc;
#pragma unroll
            for (int r = 0; r < 16; ++r) sacc[r] = 0.0f;
            __builtin_amdgcn_s_setprio(1);
#pragma unroll
            for (int ch = 0; ch < 4; ++ch) {
                f16x8 ka = *(const f16x8*)kvslotc(kb, ktile * 16 + (q32 >> 1), q32 & 1, ch * 2 + hi);
                sacc = mfma32(ka, qf[ch], sacc);
            }
            __builtin_amdgcn_s_setprio(0);

            // ---- softmax + pack to f16 pairs
            u32 ownA[4], ownB[4], gotA[4], gotB[4];
#pragma unroll
            for (int rg = 0; rg < 4; ++rg) {
                f32x4 mk = *(const f32x4*)(mkb + ((ktile * 8 + 2 * rg + hi) << 4));
                float z0 = fexp2(sacc[rg * 4 + 0]);
                float z1 = fexp2(sacc[rg * 4 + 1]);
                float z2 = fexp2(sacc[rg * 4 + 2]);
                float z3 = fexp2(sacc[rg * 4 + 3]);
                float p0 = fexp2(fmaf(negl2, frcp(z0 + 1.f), mk[0]));
                float p1 = fexp2(fmaf(negl2, frcp(z1 + 1.f), mk[1]));
                float p2 = fexp2(fmaf(negl2, frcp(z2 + 1.f), mk[2]));
                float p3 = fexp2(fmaf(negl2, frcp(z3 + 1.f), mk[3]));
                ownA[rg] = __builtin_bit_cast(u32, __builtin_amdgcn_cvt_pkrtz(p0, p1));
                ownB[rg] = __builtin_bit_cast(u32, __builtin_amdgcn_cvt_pkrtz(p2, p3));
            }
#pragma unroll
            for (int rg = 0; rg < 4; ++rg) {
                gotA[rg] = (u32)__shfl_xor((int)ownA[rg], 32, 64);
                gotB[rg] = (u32)__shfl_xor((int)ownB[rg], 32, 64);
            }

            // ---- PV (O^T) + MFMA denominator
#pragma unroll
            for (int c = 0; c < 2; ++c) {
                u32x4 pw;
                pw[0] = hi ? gotA[2 * c + 1] : ownA[2 * c];
                pw[1] = hi ? gotB[2 * c + 1] : ownB[2 * c];
                pw[2] = hi ? ownA[2 * c + 1] : gotA[2 * c];
                pw[3] = hi ? ownB[2 * c + 1] : gotB[2 * c];
                f16x8 pf = __builtin_bit_cast(f16x8, pw);
                const int kc = ktile * 2 + c;
                __builtin_amdgcn_s_setprio(1);
                dacc = mfma32(ones, pf, dacc);   // every lane gets its q's sum
#pragma unroll
                for (int t = 0; t < 2; ++t) {
                    f16x8 va = *(const f16x8*)kvslotc(vtb, t * 16 + (q32 >> 1), q32 & 1, kc * 2 + hi);
                    oaccT[t] = mfma32(va, pf, oaccT[t]);
                }
                __builtin_amdgcn_s_setprio(0);
            }
        }
        cur ^= 1;
    }

    // ---- epilogue: store O into the out_gemm X tile image (pre-swizzled, 16KB tiles)
    const float dd = frcp(dacc[0]);
    const int mb = b * 16 + qt * 2 + (wid >> 2);
    const int rr = (wid & 3) * 32 + q32;
    char* xt = Ximg + ((size_t)(mb * 16 + h)) * 16384 + rr * 128;
    const int rx = (rr & 7) << 4;
#pragma unroll
    for (int t = 0; t < 2; ++t)
#pragma unroll
        for (int rg = 0; rg < 4; ++rg) {
            u32x2 w;
            w[0] = __builtin_bit_cast(u32, __builtin_amdgcn_cvt_pkrtz(
                       oaccT[t][rg * 4 + 0] * dd, oaccT[t][rg * 4 + 1] * dd));
            w[1] = __builtin_bit_cast(u32, __builtin_amdgcn_cvt_pkrtz(
                       oaccT[t][rg * 4 + 2] * dd, oaccT[t][rg * 4 + 3] * dd));
            *(u32x2*)(xt + (((t * 4 + rg) << 4) ^ rx) + hi * 8) = w;
        }
}

// ---------- out = X @ W^T: 512 threads (8 waves, 4x2), dbuf gl_lds images ----------
__global__ __launch_bounds__(512, 4) void out_gemm(
    const char* __restrict__ Ximg, const char* __restrict__ Wt,
    float* __restrict__ out)
{
    __shared__ __align__(16) char buf[2][32768];   // 16KB X tile + 16KB W tiles

    const int tid = threadIdx.x;
    const int l   = tid & 63;
    const int wid = tid >> 6;        // 8 waves
    const int l15 = l & 15;
    const int l4  = l >> 4;
    const int wm  = wid >> 1, wn = wid & 1;   // wave grid 4 x 2: 32 rows x 64 cols

    // per-XCD column panel
    const int orig = blockIdx.x;
    const int work = (orig & 7) * 64 + (orig >> 3);
    const int mb = work & 63, nb = work >> 6;

    const char* xt = Ximg + (size_t)(mb * 16) * 16384;       // 16 kt tiles of 16KB
    const char* w0 = Wt + (size_t)((nb * 2) * 16) * 8192;
    const char* w1 = Wt + (size_t)((nb * 2 + 1) * 16) * 8192;

    const f32x4 fzero = {0.f, 0.f, 0.f, 0.f};
    f32x4 acc[2][4];
#pragma unroll
    for (int m = 0; m < 2; ++m)
#pragma unroll
        for (int n = 0; n < 4; ++n) acc[m][n] = fzero;

    // stage one kt: 16 X chunks + 16 W chunks of 1KB, 4 per wave, all gl_lds16
#define STAGE_GEMM(bf, kt)                                                        \
    {                                                                             \
        _Pragma("unroll")                                                         \
        for (int i = 0; i < 2; ++i) {                                             \
            const int c = wid * 2 + i;                                            \
            gl_lds16(xt + (size_t)(kt) * 16384 + c * 1024 + l * 16,               \
                     (bf) + c * 1024);                                            \
        }                                                                         \
        _Pragma("unroll")                                                         \
        for (int i = 0; i < 2; ++i) {                                             \
            const int c = wid * 2 + i;                                            \
            const char* src = (c < 8) ? (w0 + (size_t)(kt) * 8192 + c * 1024)     \
                                      : (w1 + (size_t)(kt) * 8192 + (c - 8) * 1024); \
            gl_lds16(src + l * 16, (bf) + 16384 + c * 1024);                      \
        }                                                                         \
    }

    STAGE_GEMM(buf[0], 0);
    int cur = 0;
    for (int kt = 0; kt < 16; ++kt) {
        drain_barrier();
        if (kt < 15)
            STAGE_GEMM(buf[cur ^ 1], kt + 1);

        char* xsb = buf[cur];
        char* wsb = buf[cur] + 16384;

        f16x8 af[2][2], bfr[4][2];
#pragma unroll
        for (int m = 0; m < 2; ++m)
#pragma unroll
            for (int kc = 0; kc < 2; ++kc)
                af[m][kc] = *(const f16x8*)swz(xsb, wm * 32 + m * 16 + l15, kc * 64 + l4 * 16);
#pragma unroll
        for (int n = 0; n < 4; ++n)
#pragma unroll
            for (int kc = 0; kc < 2; ++kc)
                bfr[n][kc] = *(const f16x8*)swz(wsb, wn * 64 + n * 16 + l15, kc * 64 + l4 * 16);

        __builtin_amdgcn_s_setprio(1);
#pragma unroll
        for (int m = 0; m < 2; ++m)
#pragma unroll
            for (int n = 0; n < 4; ++n) {
                acc[m][n] = mfma16h(af[m][0], bfr[n][0], acc[m][n]);
                acc[m][n] = mfma16h(af[m][1], bfr[n][1], acc[m][n]);
            }
        __builtin_amdgcn_s_setprio(0);
        cur ^= 1;
    }
#undef STAGE_GEMM

#pragma unroll
    for (int m = 0; m < 2; ++m)
#pragma unroll
        for (int n = 0; n < 4; ++n)
#pragma unroll
            for (int r = 0; r < 4; ++r)
                out[(size_t)(mb * 128 + wm * 32 + m * 16 + l4 * 4 + r) * Esz +
                    nb * 128 + wn * 64 + n * 16 + l15] = acc[m][n][r];
}

extern "C" void kernel_launch(void* const* d_in, const int* in_sizes, int n_in,
                              void* d_out, int out_size, void* d_ws, size_t ws_size,
                              hipStream_t stream) {
    const float* Q     = (const float*)d_in[0];
    const float* K     = (const float*)d_in[1];
    const float* V     = (const float*)d_in[2];
    const int*   mask  = (const int*)d_in[3];
    const float* W     = (const float*)d_in[4];
    const float* scale = (const float*)d_in[5];
    const float* logC  = (const float*)d_in[6];

    char*  ws   = (char*)d_ws;          // ~53 MB scratch
    char*  KVt  = ws;
    char*  Wt   = ws + WT_OFF;
    char*  Ximg = ws + X_OFF;           // 1024 tiles x 16KB = 16MB
    int*   nkp  = (int*)(ws + NKEPT_OFF);
    float* out  = (float*)d_out;

    prep_all<<<dim3(NKT, Hsz, Bsz + 1), 256, 0, stream>>>(K, V, mask, scale, W, KVt, Wt, nkp);
    attn_kernel<<<512, 512, 0, stream>>>(KVt, Q, nkp, logC, Ximg);
    out_gemm<<<512, 512, 0, stream>>>(Ximg, Wt, out);
}

// Round 18
// 120.812 us; speedup vs baseline: 1.0477x; 1.0477x over previous
//
#include <hip/hip_runtime.h>
#include <hip/hip_bf16.h>

#define Bsz 4
#define Ssz 2048
#define Esz 1024
#define Hsz 16
#define DHsz 64

// KV tile (64 keys, fp16): K 8KB | VT 8KB | padflag(f32) 256B
#define TILE_B 16640
#define NKT    (Ssz / 64)                    // 32 tiles max (~17 used)
#define WT_OFF   34078720                    // 256 W tiles x 8KB = 2MB
#define X_OFF    36175872                    // X tile images: 1024 x 16KB = 16MB
#define NKEPT_OFF 52953088                   // 4 ints

typedef _Float16 f16x8 __attribute__((ext_vector_type(8)));
typedef float    f32x4  __attribute__((ext_vector_type(4)));
typedef float    f32x16 __attribute__((ext_vector_type(16)));
typedef unsigned int u32;
typedef u32 u32x2 __attribute__((ext_vector_type(2)));
typedef u32 u32x4 __attribute__((ext_vector_type(4)));

static __device__ __forceinline__ f32x16 mfma32(f16x8 a, f16x8 b, f32x16 c) {
    return __builtin_amdgcn_mfma_f32_32x32x16_f16(a, b, c, 0, 0, 0);
}
static __device__ __forceinline__ f32x4 mfma16h(f16x8 a, f16x8 b, f32x4 c) {
    return __builtin_amdgcn_mfma_f32_16x16x32_f16(a, b, c, 0, 0, 0);
}

// Explicit drain before barrier (rule #18): replay-safe dbuf.
static __device__ __forceinline__ void drain_barrier() {
    asm volatile("s_waitcnt vmcnt(0) lgkmcnt(0)" ::: "memory");
    __builtin_amdgcn_sched_barrier(0);
    __syncthreads();
}

// 64x64 fp16 tile in 256B rows (2 keys/row, 16 slots of 16B); conflict-free
// (SQ_LDS_BANK_CONFLICT == 0 measured, rounds 8-17).
static __device__ __forceinline__ char* kvslot(char* base, int r2, int p, int j) {
    int s = ((((j & 4) << 1) | (p << 2) | (j & 3)) ^ (r2 & 15));
    return base + r2 * 256 + (s << 4);
}
static __device__ __forceinline__ const char* kvslotc(const char* base, int r2, int p, int j) {
    int s = ((((j & 4) << 1) | (p << 2) | (j & 3)) ^ (r2 & 15));
    return base + r2 * 256 + (s << 4);
}

// 128B-row swizzle (out_gemm 16x16 fragments: 2-way = free).
static __device__ __forceinline__ char* swz(char* base, int row, int colByte) {
    return base + row * 128 + (colByte ^ ((row & 7) << 4));
}

typedef const unsigned int __attribute__((address_space(1))) as1_u32;
typedef unsigned int __attribute__((address_space(3))) as3_u32;
static __device__ __forceinline__ void gl_lds16(const void* g, void* l) {
    __builtin_amdgcn_global_load_lds((as1_u32*)g, (as3_u32*)l, 16, 0, 0);
}
static __device__ __forceinline__ void gl_lds4(const void* g, void* l) {
    __builtin_amdgcn_global_load_lds((as1_u32*)g, (as3_u32*)l, 4, 0, 0);
}

static __device__ __forceinline__ float fexp2(float x) {
#if __has_builtin(__builtin_amdgcn_exp2f)
    return __builtin_amdgcn_exp2f(x);
#else
    return __expf(x * 0.6931471805599453f);
#endif
}
static __device__ __forceinline__ float frcp(float x) {
#if __has_builtin(__builtin_amdgcn_rcpf)
    return __builtin_amdgcn_rcpf(x);
#else
    return __fdividef(1.0f, x);
#endif
}

// ---------- prepass (single launch): z<4 -> KV gather (inline mask scan);
//                                     z==4 -> W fp32->fp16 tile images ----------
__global__ __launch_bounds__(256) void prep_all(
    const float* __restrict__ K, const float* __restrict__ V,
    const int* __restrict__ mask, const float* __restrict__ scale_p,
    const float* __restrict__ W,
    char* __restrict__ KVt, char* __restrict__ Wt, int* __restrict__ nkept)
{
    const int tid = threadIdx.x;

    if (blockIdx.z == Bsz) {   // ---- W conversion slice (256 of 512 blocks)
        const int w = blockIdx.y * 32 + blockIdx.x;
        if (w >= 256) return;
        const int kt = w & 15, nt = w >> 4;
        char* tile = Wt + (size_t)(nt * 16 + kt) * 8192;
        const int n = tid >> 2, seg = tid & 3;
        const float* wp = W + (size_t)(nt * 64 + n) * Esz + kt * 64 + seg * 16;
        f16x8 t[2];
#pragma unroll
        for (int hf = 0; hf < 2; ++hf) {
            f32x4 a = *(const f32x4*)(wp + hf * 8);
            f32x4 c = *(const f32x4*)(wp + hf * 8 + 4);
#pragma unroll
            for (int i = 0; i < 8; ++i) t[hf][i] = (_Float16)((i < 4) ? a[i] : c[i - 4]);
        }
        const int x = (n & 7) << 4;
        *(f16x8*)(tile + n * 128 + ((seg * 32) ^ x))      = t[0];
        *(f16x8*)(tile + n * 128 + ((seg * 32 + 16) ^ x)) = t[1];
        return;
    }

    // ---- KV slice: inline per-block compaction scan (wave 0), then gather
    const int kt = blockIdx.x, h = blockIdx.y, b = blockIdx.z;
    __shared__ int kidx_s[Ssz];
    __shared__ int nk_s;

    if (tid < 64) {
        int mreg[32];
#pragma unroll
        for (int c = 0; c < 32; ++c)
            mreg[c] = mask[(size_t)b * Ssz + c * 64 + tid];
        int base = 0;
#pragma unroll
        for (int c = 0; c < 32; ++c) {
            const bool keep = (mreg[c] == 0);
            const unsigned long long bal = __ballot(keep);
            const int pos = base + (int)__popcll(bal & ((1ull << tid) - 1ull));
            if (keep) kidx_s[pos] = c * 64 + tid;
            base += (int)__popcll(bal);
        }
        if (tid == 0) {
            nk_s = base;
            if (kt == 0 && h == 0) nkept[b] = base;
        }
    }
    __syncthreads();
    const int nk = nk_s;
    if (kt >= ((nk + 63) >> 6)) return;

    char* tile = KVt + (size_t)((b * Hsz + h) * NKT + kt) * TILE_B;
    const float k1l2 = scale_p[0] * 0.25f * 1.4426950408889634f;  // folded QK scale

    {   // K: thread -> compact key i, d-chunks 2seg, 2seg+1
        const int i = tid >> 2, seg = tid & 3;
        const int jj = kt * 64 + i;
        f16x8 t[2] = {{0,0,0,0,0,0,0,0},{0,0,0,0,0,0,0,0}};
        if (jj < nk) {
            const int src = kidx_s[jj];
            const float* kp = K + ((size_t)b * Ssz + src) * Esz + h * DHsz + seg * 16;
#pragma unroll
            for (int hf = 0; hf < 2; ++hf) {
                f32x4 a = *(const f32x4*)(kp + hf * 8);
                f32x4 c = *(const f32x4*)(kp + hf * 8 + 4);
#pragma unroll
                for (int q = 0; q < 8; ++q)
                    t[hf][q] = (_Float16)(((q < 4) ? a[q] : c[q - 4]) * k1l2);
            }
        }
#pragma unroll
        for (int hf = 0; hf < 2; ++hf)
            *(f16x8*)kvslot(tile, i >> 1, i & 1, seg * 2 + hf) = t[hf];
    }
    {   // V^T: thread -> dh row d, compact key chunks 2ks, 2ks+1
        const int d = tid & 63, ks = tid >> 6;
        f16x8 t[2] = {{0,0,0,0,0,0,0,0},{0,0,0,0,0,0,0,0}};
#pragma unroll
        for (int j = 0; j < 16; ++j) {
            const int jj = kt * 64 + ks * 16 + j;
            if (jj < nk) {
                const int src = kidx_s[jj];
                t[j >> 3][j & 7] = (_Float16)V[((size_t)b * Ssz + src) * Esz + h * DHsz + d];
            }
        }
#pragma unroll
        for (int hf = 0; hf < 2; ++hf)
            *(f16x8*)kvslot(tile + 8192, d >> 1, d & 1, ks * 2 + hf) = t[hf];
    }
    if (tid < 64)
        *(float*)(tile + 16384 + tid * 4) = (kt * 64 + tid < nk) ? 0.0f : -100000.0f;
}

// ---------- fused attention: 256 q/block (8 waves) — frozen best geometry ----------
static __device__ __forceinline__ void stage(char* buf, const char* tile, int wid, int lane) {
#pragma unroll
    for (int i = 0; i < 2; ++i) {
        const int c = wid * 2 + i;
        gl_lds16(tile + c * 1024 + lane * 16, buf + c * 1024);
    }
    if (wid == 0)
        gl_lds4(tile + 16384 + lane * 4, buf + 16384);
}

__global__ __launch_bounds__(512, 4) void attn_kernel(
    const char* __restrict__ KVt, const float* __restrict__ Q,
    const int* __restrict__ nkept, const float* __restrict__ logC_p,
    char* __restrict__ Ximg)
{
    __shared__ __align__(16) char kvb[2][TILE_B];

    const int tid = threadIdx.x;
    const int l   = tid & 63;
    const int wid = tid >> 6;        // 8 waves, each owns 32 queries
    const int q32 = l & 31;
    const int hi  = l >> 5;

    // XCD-chunked swizzle: 8 q-blocks of one (b,h) -> same XCD
    const int orig = blockIdx.x;
    const int work = (orig & 7) * 64 + (orig >> 3);
    const int bh = work >> 3, qt = work & 7;
    const int b = bh >> 4, h = bh & 15;

    const float LOG2E = 1.4426950408889634f;
    const float C     = __expf(logC_p[0]);
    const float negl2 = -2.0f * C * LOG2E;        // p = 2^(negl2/(z+1) + padlog)
    const int   nkt   = (nkept[b] + 63) >> 6;     // dynamic tile count (~17)

    const char* tiles = KVt + (size_t)bh * NKT * TILE_B;

    // Q fragments: qf[ch][j] = Q[qt*256+wid*32+q32][ch*16 + hi*8 + j]
    f16x8 qf[4];
    {
        const float* qp = Q + ((size_t)b * Ssz + qt * 256 + wid * 32 + q32) * Esz + h * DHsz + hi * 8;
#pragma unroll
        for (int ch = 0; ch < 4; ++ch) {
            f32x4 v0 = *(const f32x4*)(qp + ch * 16);
            f32x4 v1 = *(const f32x4*)(qp + ch * 16 + 4);
#pragma unroll
            for (int i = 0; i < 8; ++i)
                qf[ch][i] = (_Float16)((i < 4) ? v0[i] : v1[i - 4]);
        }
    }

    const f16x8 ones = {(_Float16)1.f, (_Float16)1.f, (_Float16)1.f, (_Float16)1.f,
                        (_Float16)1.f, (_Float16)1.f, (_Float16)1.f, (_Float16)1.f};

    f32x16 oaccT[2], dacc;
#pragma unroll
    for (int t = 0; t < 2; ++t)
#pragma unroll
        for (int r = 0; r < 16; ++r) oaccT[t][r] = 0.0f;
#pragma unroll
    for (int r = 0; r < 16; ++r) dacc[r] = 0.0f;

    stage(kvb[0], tiles, wid, l);
    int cur = 0;
    for (int kt = 0; kt < nkt; ++kt) {
        drain_barrier();                       // buf[cur] fully staged for ALL waves
        if (kt < nkt - 1)
            stage(kvb[cur ^ 1], tiles + (size_t)(kt + 1) * TILE_B, wid, l);

        char* kb  = kvb[cur];
        char* vtb = kb + 8192;
        const char* mkb = kb + 16384;

#pragma unroll
        for (int ktile = 0; ktile < 2; ++ktile) {
            // ---- QK^T (swapped, K pre-scaled): D[key][query]
            f32x16 sacc;
#pragma unroll
            for (int r = 0; r < 16; ++r) sacc[r] = 0.0f;
            __builtin_amdgcn_s_setprio(1);
#pragma unroll
            for (int ch = 0; ch < 4; ++ch) {
                f16x8 ka = *(const f16x8*)kvslotc(kb, ktile * 16 + (q32 >> 1), q32 & 1, ch * 2 + hi);
                sacc = mfma32(ka, qf[ch], sacc);
            }
            __builtin_amdgcn_s_setprio(0);

            // ---- softmax + pack to f16 pairs
            u32 ownA[4], ownB[4], gotA[4], gotB[4];
#pragma unroll
            for (int rg = 0; rg < 4; ++rg) {
                f32x4 mk = *(const f32x4*)(mkb + ((ktile * 8 + 2 * rg + hi) << 4));
                float z0 = fexp2(sacc[rg * 4 + 0]);
                float z1 = fexp2(sacc[rg * 4 + 1]);
                float z2 = fexp2(sacc[rg * 4 + 2]);
                float z3 = fexp2(sacc[rg * 4 + 3]);
                float p0 = fexp2(fmaf(negl2, frcp(z0 + 1.f), mk[0]));
                float p1 = fexp2(fmaf(negl2, frcp(z1 + 1.f), mk[1]));
                float p2 = fexp2(fmaf(negl2, frcp(z2 + 1.f), mk[2]));
                float p3 = fexp2(fmaf(negl2, frcp(z3 + 1.f), mk[3]));
                ownA[rg] = __builtin_bit_cast(u32, __builtin_amdgcn_cvt_pkrtz(p0, p1));
                ownB[rg] = __builtin_bit_cast(u32, __builtin_amdgcn_cvt_pkrtz(p2, p3));
            }
#pragma unroll
            for (int rg = 0; rg < 4; ++rg) {
                gotA[rg] = (u32)__shfl_xor((int)ownA[rg], 32, 64);
                gotB[rg] = (u32)__shfl_xor((int)ownB[rg], 32, 64);
            }

            // ---- PV (O^T) + MFMA denominator
#pragma unroll
            for (int c = 0; c < 2; ++c) {
                u32x4 pw;
                pw[0] = hi ? gotA[2 * c + 1] : ownA[2 * c];
                pw[1] = hi ? gotB[2 * c + 1] : ownB[2 * c];
                pw[2] = hi ? ownA[2 * c + 1] : gotA[2 * c];
                pw[3] = hi ? ownB[2 * c + 1] : gotB[2 * c];
                f16x8 pf = __builtin_bit_cast(f16x8, pw);
                const int kc = ktile * 2 + c;
                __builtin_amdgcn_s_setprio(1);
                dacc = mfma32(ones, pf, dacc);   // every lane gets its q's sum
#pragma unroll
                for (int t = 0; t < 2; ++t) {
                    f16x8 va = *(const f16x8*)kvslotc(vtb, t * 16 + (q32 >> 1), q32 & 1, kc * 2 + hi);
                    oaccT[t] = mfma32(va, pf, oaccT[t]);
                }
                __builtin_amdgcn_s_setprio(0);
            }
        }
        cur ^= 1;
    }

    // ---- epilogue: store O into the out_gemm X tile image (pre-swizzled, 16KB tiles)
    const float dd = frcp(dacc[0]);
    const int mb = b * 16 + qt * 2 + (wid >> 2);
    const int rr = (wid & 3) * 32 + q32;
    char* xt = Ximg + ((size_t)(mb * 16 + h)) * 16384 + rr * 128;
    const int rx = (rr & 7) << 4;
#pragma unroll
    for (int t = 0; t < 2; ++t)
#pragma unroll
        for (int rg = 0; rg < 4; ++rg) {
            u32x2 w;
            w[0] = __builtin_bit_cast(u32, __builtin_amdgcn_cvt_pkrtz(
                       oaccT[t][rg * 4 + 0] * dd, oaccT[t][rg * 4 + 1] * dd));
            w[1] = __builtin_bit_cast(u32, __builtin_amdgcn_cvt_pkrtz(
                       oaccT[t][rg * 4 + 2] * dd, oaccT[t][rg * 4 + 3] * dd));
            *(u32x2*)(xt + (((t * 4 + rg) << 4) ^ rx) + hi * 8) = w;
        }
}

// ---------- out = X @ W^T: both operands pre-swizzled images, dbuf gl_lds ----------
__global__ __launch_bounds__(256) void out_gemm(
    const char* __restrict__ Ximg, const char* __restrict__ Wt,
    float* __restrict__ out)
{
    __shared__ __align__(16) char buf[2][32768];   // 16KB X tile + 16KB W tiles

    const int tid = threadIdx.x;
    const int l   = tid & 63;
    const int wid = tid >> 6;
    const int l15 = l & 15;
    const int l4  = l >> 4;
    const int wm  = wid >> 1, wn = wid & 1;

    // per-XCD column panel
    const int orig = blockIdx.x;
    const int work = (orig & 7) * 64 + (orig >> 3);
    const int mb = work & 63, nb = work >> 6;

    const char* xt = Ximg + (size_t)(mb * 16) * 16384;       // 16 kt tiles of 16KB
    const char* w0 = Wt + (size_t)((nb * 2) * 16) * 8192;
    const char* w1 = Wt + (size_t)((nb * 2 + 1) * 16) * 8192;

    const f32x4 fzero = {0.f, 0.f, 0.f, 0.f};
    f32x4 acc[4][4];
#pragma unroll
    for (int m = 0; m < 4; ++m)
#pragma unroll
        for (int n = 0; n < 4; ++n) acc[m][n] = fzero;

    // stage one kt: 16 X chunks + 16 W chunks of 1KB, 8 per wave, all gl_lds16
#define STAGE_GEMM(bf, kt)                                                        \
    {                                                                             \
        _Pragma("unroll")                                                         \
        for (int i = 0; i < 4; ++i) {                                             \
            const int c = wid * 4 + i;                                            \
            gl_lds16(xt + (size_t)(kt) * 16384 + c * 1024 + l * 16,               \
                     (bf) + c * 1024);                                            \
        }                                                                         \
        _Pragma("unroll")                                                         \
        for (int i = 0; i < 4; ++i) {                                             \
            const int c = wid * 4 + i;                                            \
            const char* src = (c < 8) ? (w0 + (size_t)(kt) * 8192 + c * 1024)     \
                                      : (w1 + (size_t)(kt) * 8192 + (c - 8) * 1024); \
            gl_lds16(src + l * 16, (bf) + 16384 + c * 1024);                      \
        }                                                                         \
    }

    STAGE_GEMM(buf[0], 0);
    int cur = 0;
    for (int kt = 0; kt < 16; ++kt) {
        drain_barrier();
        if (kt < 15)
            STAGE_GEMM(buf[cur ^ 1], kt + 1);

        char* xsb = buf[cur];
        char* wsb = buf[cur] + 16384;

        f16x8 af[4][2], bfr[4][2];
#pragma unroll
        for (int m = 0; m < 4; ++m)
#pragma unroll
            for (int kc = 0; kc < 2; ++kc)
                af[m][kc] = *(const f16x8*)swz(xsb, wm * 64 + m * 16 + l15, kc * 64 + l4 * 16);
#pragma unroll
        for (int n = 0; n < 4; ++n)
#pragma unroll
            for (int kc = 0; kc < 2; ++kc)
                bfr[n][kc] = *(const f16x8*)swz(wsb, wn * 64 + n * 16 + l15, kc * 64 + l4 * 16);

        __builtin_amdgcn_s_setprio(1);
#pragma unroll
        for (int m = 0; m < 4; ++m)
#pragma unroll
            for (int n = 0; n < 4; ++n) {
                acc[m][n] = mfma16h(af[m][0], bfr[n][0], acc[m][n]);
                acc[m][n] = mfma16h(af[m][1], bfr[n][1], acc[m][n]);
            }
        __builtin_amdgcn_s_setprio(0);
        cur ^= 1;
    }
#undef STAGE_GEMM

#pragma unroll
    for (int m = 0; m < 4; ++m)
#pragma unroll
        for (int n = 0; n < 4; ++n)
#pragma unroll
            for (int r = 0; r < 4; ++r)
                out[(size_t)(mb * 128 + wm * 64 + m * 16 + l4 * 4 + r) * Esz +
                    nb * 128 + wn * 64 + n * 16 + l15] = acc[m][n][r];
}

extern "C" void kernel_launch(void* const* d_in, const int* in_sizes, int n_in,
                              void* d_out, int out_size, void* d_ws, size_t ws_size,
                              hipStream_t stream) {
    const float* Q     = (const float*)d_in[0];
    const float* K     = (const float*)d_in[1];
    const float* V     = (const float*)d_in[2];
    const int*   mask  = (const int*)d_in[3];
    const float* W     = (const float*)d_in[4];
    const float* scale = (const float*)d_in[5];
    const float* logC  = (const float*)d_in[6];

    char*  ws   = (char*)d_ws;          // ~53 MB scratch
    char*  KVt  = ws;
    char*  Wt   = ws + WT_OFF;
    char*  Ximg = ws + X_OFF;           // 1024 tiles x 16KB = 16MB
    int*   nkp  = (int*)(ws + NKEPT_OFF);
    float* out  = (float*)d_out;

    prep_all<<<dim3(NKT, Hsz, Bsz + 1), 256, 0, stream>>>(K, V, mask, scale, W, KVt, Wt, nkp);
    attn_kernel<<<512, 512, 0, stream>>>(KVt, Q, nkp, logC, Ximg);
    out_gemm<<<512, 256, 0, stream>>>(Ximg, Wt, out);
}